// Round 8
// baseline (3815.240 us; speedup 1.0000x reference)
//
#include <hip/hip_runtime.h>
#include <stdint.h>

#define TAGS 29
#define START_TAG 27
#define STOP_TAG 28
#define BB 64
#define LL 1024
#define DD 1024
#define HH 512
#define FSTRIDE 32   // padded feats row stride (floats)

typedef float f2 __attribute__((ext_vector_type(2)));

// ---------------------------------------------------------------------------
// XLA EmitFastTanh clone, f32, with_fma=false (CPU elemental emitter config):
// separate mul/add roundings, clamp +-7.90531110763549805, P13/Q6 Horner,
// |x|<4e-4 -> x. contract(off) inside the body. PROVEN bit-exact (r3/r5).
// ---------------------------------------------------------------------------
__device__ __forceinline__ float xla_tanh_f32(float x) {
#pragma clang fp contract(off)
  const float kMax = 7.90531110763549805f;
  float xc = fminf(fmaxf(x, -kMax), kMax);
  float x2 = xc * xc;
  float p = x2 * -2.76076847742355e-16f + 2.00018790482477e-13f;
  p = x2 * p + -8.60467152213735e-11f;
  p = x2 * p + 5.12229709037114e-08f;
  p = x2 * p + 1.48572235717979e-05f;
  p = x2 * p + 6.37261928875436e-04f;
  p = x2 * p + 4.89352455891786e-03f;
  p = xc * p;
  float q = x2 * 1.19825839466702e-06f + 1.18534705686654e-04f;
  q = x2 * q + 2.26843463243900e-03f;
  q = x2 * q + 4.89352518554385e-03f;
  float r = p / q;                       // IEEE div
  return (fabsf(x) < 4.0e-4f) ? x : r;
}

// ---------------------------------------------------------------------------
// Kernel 1: fused MLP  feats = tanh(X@W1 + b1) @ W2 + b2
// EXACT r5 structure (passed, absmax=0). Only change: launch_bounds(512,4)
// -> (512,1). r5 counters showed the (512,4) 64-VGPR cap spilled the ~130-reg
// live set (WRITE_SIZE 1.97 GB of scratch traffic). Cap 256 -> no spill.
// contract(off): Eigen (AVX, no FMA) sequential-k mul-then-add chain.
// Packed f32 (v_pk_mul/v_pk_add) = 2 independent IEEE lanes, bit-identical.
// ---------------------------------------------------------------------------
__global__ __launch_bounds__(512, 1) void mlp_kernel(
    const float* __restrict__ X, const float* __restrict__ W1,
    const float* __restrict__ b1, const float* __restrict__ W2,
    const float* __restrict__ b2, float* __restrict__ feats)
{
#pragma clang fp contract(off)
  __shared__ __align__(16) float smem[18464];   // 73856 B -> 2 blocks/CU
  float* xs = smem;               // [32][65]  k-major X tile
  float* wl = smem + 32 * 65;     // [32][512] W1 tile
  float* hs = smem;               // [64][260] half of h (reused)

  const int tid  = threadIdx.x;
  const int row0 = blockIdx.x * 64;
  const int rg = tid >> 6, cg = tid & 63;      // 8 row-groups x 64 col-groups
  const int xr = tid >> 3, xk4 = tid & 7;      // X loader
  const int wc4 = tid & 127, wk0 = tid >> 7;   // W loader

  f2 acc[8][4];                                // rows x {2+2 | 2+2} packed cols
#pragma unroll
  for (int i = 0; i < 8; ++i)
#pragma unroll
    for (int j = 0; j < 4; ++j) acc[i][j] = (f2)(0.f);

  float4 xv = *(const float4*)(X + (size_t)(row0 + xr) * DD + xk4 * 4);
  float4 wv[8];
#pragma unroll
  for (int j = 0; j < 8; ++j)
    wv[j] = *(const float4*)(W1 + (size_t)(wk0 + j * 4) * HH + wc4 * 4);

  for (int kb = 0; kb < DD; kb += 32) {
    __syncthreads();
    xs[(xk4 * 4 + 0) * 65 + xr] = xv.x;
    xs[(xk4 * 4 + 1) * 65 + xr] = xv.y;
    xs[(xk4 * 4 + 2) * 65 + xr] = xv.z;
    xs[(xk4 * 4 + 3) * 65 + xr] = xv.w;
#pragma unroll
    for (int j = 0; j < 8; ++j)
      *(float4*)(wl + (wk0 + j * 4) * HH + wc4 * 4) = wv[j];
    __syncthreads();
    if (kb + 32 < DD) {
      xv = *(const float4*)(X + (size_t)(row0 + xr) * DD + (kb + 32) + xk4 * 4);
#pragma unroll
      for (int j = 0; j < 8; ++j)
        wv[j] = *(const float4*)(W1 + (size_t)(kb + 32 + wk0 + j * 4) * HH + wc4 * 4);
    }
#pragma unroll 4
    for (int k = 0; k < 32; ++k) {
      float4 a0 = *(float4*)(xs + k * 65 + rg * 8);        // broadcast (uniform)
      float4 a1 = *(float4*)(xs + k * 65 + rg * 8 + 4);
      float4 b0 = *(float4*)(wl + k * HH + cg * 4);        // contiguous b128
      float4 b1v = *(float4*)(wl + k * HH + 256 + cg * 4); // contiguous b128
      float av[8] = {a0.x, a0.y, a0.z, a0.w, a1.x, a1.y, a1.z, a1.w};
      f2 bv[4] = {{b0.x, b0.y}, {b0.z, b0.w}, {b1v.x, b1v.y}, {b1v.z, b1v.w}};
#pragma unroll
      for (int i = 0; i < 8; ++i) {
        f2 ai = {av[i], av[i]};
#pragma unroll
        for (int j = 0; j < 4; ++j) {
          f2 pr = ai * bv[j];                 // v_pk_mul_f32 (separate round)
          acc[i][j] = acc[i][j] + pr;         // v_pk_add_f32
        }
      }
    }
  }
  __syncthreads();   // staging done; smem becomes hs

  float sum[4] = {0.f, 0.f, 0.f, 0.f};

  // ---- phase A: h cols 0..255 ----
  {
    const int c0 = cg * 4;
#pragma unroll
    for (int i = 0; i < 8; ++i) {
      int r = rg * 8 + i;
      float4 hv;
      hv.x = xla_tanh_f32(acc[i][0].x + b1[c0 + 0]);
      hv.y = xla_tanh_f32(acc[i][0].y + b1[c0 + 1]);
      hv.z = xla_tanh_f32(acc[i][1].x + b1[c0 + 2]);
      hv.w = xla_tanh_f32(acc[i][1].y + b1[c0 + 3]);
      *(float4*)(hs + r * 260 + c0) = hv;
    }
  }
  __syncthreads();
#pragma unroll
  for (int it = 0; it < 4; ++it) {
    int idx = tid + it * 512;
    if (idx < 64 * TAGS) {
      int r = idx & 63, c = idx >> 6;        // c wave-uniform -> W2 scalarizes
      float s = 0.f;
#pragma unroll 4
      for (int k4 = 0; k4 < 64; ++k4) {
        float4 h4 = *(float4*)(hs + r * 260 + k4 * 4);
        float p0 = h4.x * W2[(k4 * 4 + 0) * TAGS + c]; s = s + p0;
        float p1 = h4.y * W2[(k4 * 4 + 1) * TAGS + c]; s = s + p1;
        float p2 = h4.z * W2[(k4 * 4 + 2) * TAGS + c]; s = s + p2;
        float p3 = h4.w * W2[(k4 * 4 + 3) * TAGS + c]; s = s + p3;
      }
      sum[it] = s;
    }
  }
  __syncthreads();

  // ---- phase B: h cols 256..511 ----
  {
    const int c0 = cg * 4;                   // global col = 256 + c0
#pragma unroll
    for (int i = 0; i < 8; ++i) {
      int r = rg * 8 + i;
      float4 hv;
      hv.x = xla_tanh_f32(acc[i][2].x + b1[256 + c0 + 0]);
      hv.y = xla_tanh_f32(acc[i][2].y + b1[256 + c0 + 1]);
      hv.z = xla_tanh_f32(acc[i][3].x + b1[256 + c0 + 2]);
      hv.w = xla_tanh_f32(acc[i][3].y + b1[256 + c0 + 3]);
      *(float4*)(hs + r * 260 + c0) = hv;
    }
  }
  __syncthreads();
#pragma unroll
  for (int it = 0; it < 4; ++it) {
    int idx = tid + it * 512;
    if (idx < 64 * TAGS) {
      int r = idx & 63, c = idx >> 6;
      float s = sum[it];
#pragma unroll 4
      for (int k4 = 0; k4 < 64; ++k4) {
        float4 h4 = *(float4*)(hs + r * 260 + k4 * 4);
        float p0 = h4.x * W2[(256 + k4 * 4 + 0) * TAGS + c]; s = s + p0;
        float p1 = h4.y * W2[(256 + k4 * 4 + 1) * TAGS + c]; s = s + p1;
        float p2 = h4.z * W2[(256 + k4 * 4 + 2) * TAGS + c]; s = s + p2;
        float p3 = h4.w * W2[(256 + k4 * 4 + 3) * TAGS + c]; s = s + p3;
      }
      feats[(size_t)(row0 + r) * FSTRIDE + c] = s + b2[c];
    }
  }
}

// ---------------------------------------------------------------------------
// Kernel 2: top-1 Viterbi (== nbest[...,0], proven; absmax=0 in r3/r5).
// EXACT r5 structure. Only change: launch_bounds(64) -> (64,1): the bare form
// let the allocator cap VGPR at 64 and spill the ~160-reg tournament (r5's
// ~1.5ms viterbi). Cap 512 -> no spill. The r6/r7 half-split experiment is
// REVERTED (failed twice, bug not identified by audit).
// ---------------------------------------------------------------------------
__global__ __launch_bounds__(64, 1) void viterbi_kernel(
    const float* __restrict__ feats, const float* __restrict__ trans,
    int* __restrict__ out)
{
#pragma clang fp contract(off)
  const int b = blockIdx.x;
  const int lane = threadIdx.x;
  const bool act = lane < TAGS;
  __shared__ unsigned char bp[LL][32];     // 32 KB
  __shared__ __align__(16) float pbuf[32];

  float tr[TAGS];
  const int tl = act ? lane : 0;
#pragma unroll
  for (int f = 0; f < TAGS; ++f) tr[f] = trans[f * TAGS + tl];

  const float* frow = feats + (size_t)b * LL * FSTRIDE;
  float part = act ? (frow[lane] + tr[START_TAG]) : -3.0e38f;
  if (lane >= TAGS && lane < 32) pbuf[lane] = -3.0e38f;

  float fc[8], fn[8];
#pragma unroll
  for (int d = 0; d < 8; ++d) fc[d] = act ? frow[(1 + d) * FSTRIDE + lane] : 0.f;

  for (int t0 = 1; t0 < LL; t0 += 8) {
#pragma unroll
    for (int d = 0; d < 8; ++d) {
      int t = t0 + 8 + d;
      fn[d] = (act && t < LL) ? frow[t * FSTRIDE + lane] : 0.f;
    }
#pragma unroll
    for (int d = 0; d < 8; ++d) {
      int t = t0 + d;
      if (t < LL) {
        if (act) pbuf[lane] = part;          // same-wave LDS: in-order
        float4 s0 = *(float4*)(pbuf + 0);    // broadcast reads (no conflict)
        float4 s1 = *(float4*)(pbuf + 4);
        float4 s2 = *(float4*)(pbuf + 8);
        float4 s3 = *(float4*)(pbuf + 12);
        float4 s4 = *(float4*)(pbuf + 16);
        float4 s5 = *(float4*)(pbuf + 20);
        float4 s6 = *(float4*)(pbuf + 24);
        float4 s7 = *(float4*)(pbuf + 28);
        float sv[32] = {s0.x, s0.y, s0.z, s0.w, s1.x, s1.y, s1.z, s1.w,
                        s2.x, s2.y, s2.z, s2.w, s3.x, s3.y, s3.z, s3.w,
                        s4.x, s4.y, s4.z, s4.w, s5.x, s5.y, s5.z, s5.w,
                        s6.x, s6.y, s6.z, s6.w, s7.x, s7.y, s7.z, s7.w};
        float fv = fc[d];
        float v[32];
#pragma unroll
        for (int fr = 0; fr < TAGS; ++fr)
          v[fr] = (fv + tr[fr]) + sv[fr];    // reference op order
#pragma unroll
        for (int fr = TAGS; fr < 32; ++fr) v[fr] = -3.0e38f;

        // adjacent-pair tournament: lowest index wins ties (== strict '>'
        // ascending scan). 32 -> 16 -> 8 -> 4 -> 2 -> 1.
        float tv[16]; int ti[16];
#pragma unroll
        for (int i = 0; i < 16; ++i) {
          bool w = v[2 * i + 1] > v[2 * i];
          tv[i] = w ? v[2 * i + 1] : v[2 * i];
          ti[i] = w ? 2 * i + 1 : 2 * i;
        }
#pragma unroll
        for (int i = 0; i < 8; ++i) {
          bool w = tv[2 * i + 1] > tv[2 * i];
          tv[i] = w ? tv[2 * i + 1] : tv[2 * i];
          ti[i] = w ? ti[2 * i + 1] : ti[2 * i];
        }
#pragma unroll
        for (int i = 0; i < 4; ++i) {
          bool w = tv[2 * i + 1] > tv[2 * i];
          tv[i] = w ? tv[2 * i + 1] : tv[2 * i];
          ti[i] = w ? ti[2 * i + 1] : ti[2 * i];
        }
#pragma unroll
        for (int i = 0; i < 2; ++i) {
          bool w = tv[2 * i + 1] > tv[2 * i];
          tv[i] = w ? tv[2 * i + 1] : tv[2 * i];
          ti[i] = w ? ti[2 * i + 1] : ti[2 * i];
        }
        {
          bool w = tv[1] > tv[0];
          part = w ? tv[1] : tv[0];
          int bi = w ? ti[1] : ti[0];
          if (act) bp[t][lane] = (unsigned char)bi;
        }
      }
    }
#pragma unroll
    for (int d = 0; d < 8; ++d) fc[d] = fn[d];
  }

  // final transition into STOP, lowest-from tie-break (once; serial scan ok)
  float best = -3.0e38f;
  int p0 = 0;
#pragma unroll
  for (int fr = 0; fr < TAGS; ++fr) {
    float s = __shfl(part, fr, 64);
    float v = s + trans[fr * TAGS + STOP_TAG];
    if (v > best) { best = v; p0 = fr; }
  }

  __syncthreads();
  if (lane == 0) {
    int* ob = out + (size_t)b * LL;
    int p = p0;
    ob[LL - 1] = p;
    for (int t = LL - 1; t >= 1; --t) {
      p = bp[t][p];
      ob[t - 1] = p;
    }
  }
}

// ---------------------------------------------------------------------------
extern "C" void kernel_launch(void* const* d_in, const int* in_sizes, int n_in,
                              void* d_out, int out_size, void* d_ws, size_t ws_size,
                              hipStream_t stream) {
  const float* X  = (const float*)d_in[0];
  const float* W1 = (const float*)d_in[2];
  const float* b1 = (const float*)d_in[3];
  const float* W2 = (const float*)d_in[4];
  const float* b2 = (const float*)d_in[5];
  const float* tr = (const float*)d_in[6];

  float* feats = (float*)d_ws;          // (B*L) x 32 padded fp32 rows = 8 MB
  int* out = (int*)d_out;

  mlp_kernel<<<dim3(BB * LL / 64), dim3(512), 0, stream>>>(X, W1, b1, W2, b2, feats);
  viterbi_kernel<<<dim3(BB), dim3(64), 0, stream>>>(feats, tr, out);
}

// Round 9
// 2503.684 us; speedup vs baseline: 1.5239x; 1.5239x over previous
//
#include <hip/hip_runtime.h>
#include <stdint.h>

#define TAGS 29
#define START_TAG 27
#define STOP_TAG 28
#define BB 64
#define LL 1024
#define DD 1024
#define HH 512
#define FSTRIDE 32   // padded feats row stride (floats)

typedef float f2 __attribute__((ext_vector_type(2)));

// ---------------------------------------------------------------------------
// XLA EmitFastTanh clone, f32, with_fma=false. PROVEN bit-exact (r3/r5/r8).
// ---------------------------------------------------------------------------
__device__ __forceinline__ float xla_tanh_f32(float x) {
#pragma clang fp contract(off)
  const float kMax = 7.90531110763549805f;
  float xc = fminf(fmaxf(x, -kMax), kMax);
  float x2 = xc * xc;
  float p = x2 * -2.76076847742355e-16f + 2.00018790482477e-13f;
  p = x2 * p + -8.60467152213735e-11f;
  p = x2 * p + 5.12229709037114e-08f;
  p = x2 * p + 1.48572235717979e-05f;
  p = x2 * p + 6.37261928875436e-04f;
  p = x2 * p + 4.89352455891786e-03f;
  p = xc * p;
  float q = x2 * 1.19825839466702e-06f + 1.18534705686654e-04f;
  q = x2 * q + 2.26843463243900e-03f;
  q = x2 * q + 4.89352518554385e-03f;
  float r = p / q;                       // IEEE div
  return (fabsf(x) < 4.0e-4f) ? x : r;
}

// ---------------------------------------------------------------------------
// Kernel 1: fused MLP  feats = tanh(X@W1 + b1) @ W2 + b2
// RESTRUCTURED TO FIT THE 64-VGPR CAP the allocator insists on (r5/r8 PMC:
// VGPR=64 + 1.97 GB scratch writes regardless of launch_bounds):
//   1024 threads/block, 64 rows x 512 cols tile, 4x8 outputs/thread
//   -> acc[4][4] f2 = 32 VGPRs; staging regs transient; peak live ~60-70.
// Numerics IDENTICAL to the r8-proven kernel: per-output k-ascending
// mul-then-add chain (contract off), packed f32 = 2 independent IEEE lanes,
// same phase-A/phase-B layer-2 accumulation order.
// ---------------------------------------------------------------------------
__global__ __launch_bounds__(1024)
__attribute__((amdgpu_waves_per_eu(4, 8)))
void mlp_kernel(
    const float* __restrict__ X, const float* __restrict__ W1,
    const float* __restrict__ b1, const float* __restrict__ W2,
    const float* __restrict__ b2, float* __restrict__ feats)
{
#pragma clang fp contract(off)
  __shared__ __align__(16) float smem[18464];   // 73856 B
  float* xs = smem;               // [32][65]  k-major X tile
  float* wl = smem + 32 * 65;     // [32][512] W1 tile
  float* hs = smem;               // [64][260] half of h (epilogue reuse)

  const int tid  = threadIdx.x;
  const int row0 = blockIdx.x * 64;
  const int rg = tid >> 6;        // 0..15 row-group (wave-uniform)
  const int cg = tid & 63;        // 0..63 col-group
  const int xr = tid >> 3, xk4 = tid & 7;      // X loader (tid < 512)
  const int wk0 = tid >> 7, wc4 = tid & 127;   // W loader (all 1024)

  f2 acc[4][4];                   // rows rg*4+i; cols {cg*4|256+cg*4} packed
#pragma unroll
  for (int i = 0; i < 4; ++i)
#pragma unroll
    for (int j = 0; j < 4; ++j) acc[i][j] = (f2)(0.f);

  for (int kb = 0; kb < DD; kb += 32) {
    __syncthreads();
    if (tid < 512) {              // X tile: 2048 floats, transposed store
      float4 xv = *(const float4*)(X + (size_t)(row0 + xr) * DD + kb + xk4 * 4);
      xs[(xk4 * 4 + 0) * 65 + xr] = xv.x;
      xs[(xk4 * 4 + 1) * 65 + xr] = xv.y;
      xs[(xk4 * 4 + 2) * 65 + xr] = xv.z;
      xs[(xk4 * 4 + 3) * 65 + xr] = xv.w;
    }
#pragma unroll
    for (int m = 0; m < 4; ++m) { // W1 tile: 64 KB straight copy, transient
      float4 w = *(const float4*)(W1 + (size_t)(kb + wk0 + 8 * m) * HH + wc4 * 4);
      *(float4*)(wl + (wk0 + 8 * m) * HH + wc4 * 4) = w;
    }
    __syncthreads();

#pragma unroll 4
    for (int k = 0; k < 32; ++k) {
      float4 a  = *(const float4*)(xs + k * 65 + rg * 4);       // broadcast
      float4 b0 = *(const float4*)(wl + k * HH + cg * 4);       // contig b128
      float4 b1v = *(const float4*)(wl + k * HH + 256 + cg * 4);
      float av[4] = {a.x, a.y, a.z, a.w};
      f2 bv[4] = {{b0.x, b0.y}, {b0.z, b0.w}, {b1v.x, b1v.y}, {b1v.z, b1v.w}};
#pragma unroll
      for (int i = 0; i < 4; ++i) {
        f2 ai = {av[i], av[i]};
#pragma unroll
        for (int j = 0; j < 4; ++j) {
          f2 pr = ai * bv[j];                 // v_pk_mul_f32 (separate round)
          acc[i][j] = acc[i][j] + pr;         // v_pk_add_f32
        }
      }
    }
  }
  __syncthreads();   // staging done; smem becomes hs

  float sum[2] = {0.f, 0.f};

  // ---- phase A: h cols 0..255 ----
  {
    const int c0 = cg * 4;
#pragma unroll
    for (int i = 0; i < 4; ++i) {
      int r = rg * 4 + i;
      float4 hv;
      hv.x = xla_tanh_f32(acc[i][0].x + b1[c0 + 0]);
      hv.y = xla_tanh_f32(acc[i][0].y + b1[c0 + 1]);
      hv.z = xla_tanh_f32(acc[i][1].x + b1[c0 + 2]);
      hv.w = xla_tanh_f32(acc[i][1].y + b1[c0 + 3]);
      *(float4*)(hs + r * 260 + c0) = hv;
    }
  }
  __syncthreads();
#pragma unroll
  for (int it = 0; it < 2; ++it) {
    int idx = tid + it * 1024;
    if (idx < 64 * TAGS) {
      int r = idx & 63, c = idx >> 6;        // c wave-uniform -> W2 scalarizes
      float s = 0.f;
#pragma unroll 4
      for (int k4 = 0; k4 < 64; ++k4) {
        float4 h4 = *(float4*)(hs + r * 260 + k4 * 4);
        float p0 = h4.x * W2[(k4 * 4 + 0) * TAGS + c]; s = s + p0;
        float p1 = h4.y * W2[(k4 * 4 + 1) * TAGS + c]; s = s + p1;
        float p2 = h4.z * W2[(k4 * 4 + 2) * TAGS + c]; s = s + p2;
        float p3 = h4.w * W2[(k4 * 4 + 3) * TAGS + c]; s = s + p3;
      }
      sum[it] = s;
    }
  }
  __syncthreads();

  // ---- phase B: h cols 256..511 ----
  {
    const int c0 = cg * 4;
#pragma unroll
    for (int i = 0; i < 4; ++i) {
      int r = rg * 4 + i;
      float4 hv;
      hv.x = xla_tanh_f32(acc[i][2].x + b1[256 + c0 + 0]);
      hv.y = xla_tanh_f32(acc[i][2].y + b1[256 + c0 + 1]);
      hv.z = xla_tanh_f32(acc[i][3].x + b1[256 + c0 + 2]);
      hv.w = xla_tanh_f32(acc[i][3].y + b1[256 + c0 + 3]);
      *(float4*)(hs + r * 260 + c0) = hv;
    }
  }
  __syncthreads();
#pragma unroll
  for (int it = 0; it < 2; ++it) {
    int idx = tid + it * 1024;
    if (idx < 64 * TAGS) {
      int r = idx & 63, c = idx >> 6;
      float s = sum[it];
#pragma unroll 4
      for (int k4 = 0; k4 < 64; ++k4) {
        float4 h4 = *(float4*)(hs + r * 260 + k4 * 4);
        float p0 = h4.x * W2[(256 + k4 * 4 + 0) * TAGS + c]; s = s + p0;
        float p1 = h4.y * W2[(256 + k4 * 4 + 1) * TAGS + c]; s = s + p1;
        float p2 = h4.z * W2[(256 + k4 * 4 + 2) * TAGS + c]; s = s + p2;
        float p3 = h4.w * W2[(256 + k4 * 4 + 3) * TAGS + c]; s = s + p3;
      }
      feats[(size_t)(row0 + r) * FSTRIDE + c] = s + b2[c];
    }
  }
}

// ---------------------------------------------------------------------------
// Kernel 2: top-1 Viterbi (== nbest[...,0]; r3/r5/r8-proven semantics).
// Register-diet rework to fit the 64-VGPR cap (r8: ~1.6 ms from spills):
//  - emissions staged to LDS per 64-step chunk (kills the 16 fc/fn regs)
//  - 29-wide argmax processed as 4 ascending chunks of 8 with strict-'>'
//    merge: same adds in same order, lowest-index tie-break preserved
//    (in-lane only; the r6/r7 cross-lane half-split is NOT used).
// ---------------------------------------------------------------------------
__global__ __launch_bounds__(64)
__attribute__((amdgpu_waves_per_eu(1, 4)))
void viterbi_kernel(
    const float* __restrict__ feats, const float* __restrict__ trans,
    int* __restrict__ out)
{
#pragma clang fp contract(off)
  const int b = blockIdx.x;
  const int lane = threadIdx.x;
  const bool act = lane < TAGS;
  __shared__ unsigned char bp[LL][32];       // 32 KB back-pointers
  __shared__ __align__(16) float em[2048];   // 8 KB: 64 steps x 32 tags
  __shared__ __align__(16) float pbuf[32];

  float tr[TAGS];
  const int tl = act ? lane : 0;
#pragma unroll
  for (int f = 0; f < TAGS; ++f) tr[f] = trans[f * TAGS + tl];

  const float* frow = feats + (size_t)b * LL * FSTRIDE;
  float part = act ? (frow[lane] + tr[START_TAG]) : -3.0e38f;
  if (lane >= TAGS && lane < 32) pbuf[lane] = -3.0e38f;   // pad slots, once

  for (int tc = 0; tc < LL / 64; ++tc) {
    // stage this chunk's emissions: 2048 contiguous floats -> em (flat copy)
    {
      const float* flat = frow + tc * 2048;
#pragma unroll
      for (int i = 0; i < 8; ++i) {
        float4 v4 = *(const float4*)(flat + lane * 4 + i * 256);
        *(float4*)(em + lane * 4 + i * 256) = v4;
      }
    }
    const int t0c = (tc == 0) ? 1 : tc * 64;   // t=0 is the init, skip
    const int t1c = tc * 64 + 64;
    for (int t = t0c; t < t1c; ++t) {
      float fv = em[((t & 63) << 5) + lane];
      if (act) pbuf[lane] = part;              // same-wave LDS: in-order
      const float4* pq = (const float4*)pbuf;
      float bvv = -3.0e38f;
      int bii = 0;
#pragma unroll
      for (int cch = 0; cch < 4; ++cch) {      // 'from' chunks 0..7,8..15,...
        float4 sA = pq[cch * 2 + 0];           // broadcast reads, no conflict
        float4 sB = pq[cch * 2 + 1];
        float s8[8] = {sA.x, sA.y, sA.z, sA.w, sB.x, sB.y, sB.z, sB.w};
        float v8[8];
#pragma unroll
        for (int j = 0; j < 8; ++j) {
          int fr = cch * 8 + j;
          v8[j] = (fr < TAGS) ? ((fv + tr[fr]) + s8[j])   // reference op order
                              : -3.0e38f;
        }
        // adjacent-pair tournament of 8: lowest index wins ties
        float t4[4]; int i4[4];
#pragma unroll
        for (int i = 0; i < 4; ++i) { bool w = v8[2*i+1] > v8[2*i];
          t4[i] = w ? v8[2*i+1] : v8[2*i]; i4[i] = w ? 2*i+1 : 2*i; }
        float t2[2]; int i2[2];
#pragma unroll
        for (int i = 0; i < 2; ++i) { bool w = t4[2*i+1] > t4[2*i];
          t2[i] = w ? t4[2*i+1] : t4[2*i]; i2[i] = w ? i4[2*i+1] : i4[2*i]; }
        bool w = t2[1] > t2[0];
        float cv = w ? t2[1] : t2[0];
        int   ci = (w ? i2[1] : i2[0]) + cch * 8;
        if (cv > bvv) { bvv = cv; bii = ci; }  // strict '>': ascending chunks
      }
      part = bvv;
      if (act) bp[t][lane] = (unsigned char)bii;
    }
  }

  // final transition into STOP, lowest-from tie-break (once; serial scan ok)
  float best = -3.0e38f;
  int p0 = 0;
#pragma unroll
  for (int fr = 0; fr < TAGS; ++fr) {
    float s = __shfl(part, fr, 64);
    float v = s + trans[fr * TAGS + STOP_TAG];
    if (v > best) { best = v; p0 = fr; }
  }

  __syncthreads();
  if (lane == 0) {
    int* ob = out + (size_t)b * LL;
    int p = p0;
    ob[LL - 1] = p;
    for (int t = LL - 1; t >= 1; --t) {
      p = bp[t][p];
      ob[t - 1] = p;
    }
  }
}

// ---------------------------------------------------------------------------
extern "C" void kernel_launch(void* const* d_in, const int* in_sizes, int n_in,
                              void* d_out, int out_size, void* d_ws, size_t ws_size,
                              hipStream_t stream) {
  const float* X  = (const float*)d_in[0];
  const float* W1 = (const float*)d_in[2];
  const float* b1 = (const float*)d_in[3];
  const float* W2 = (const float*)d_in[4];
  const float* b2 = (const float*)d_in[5];
  const float* tr = (const float*)d_in[6];

  float* feats = (float*)d_ws;          // (B*L) x 32 padded fp32 rows = 8 MB
  int* out = (int*)d_out;

  mlp_kernel<<<dim3(BB * LL / 64), dim3(1024), 0, stream>>>(X, W1, b1, W2, b2, feats);
  viterbi_kernel<<<dim3(BB), dim3(64), 0, stream>>>(feats, tr, out);
}

// Round 10
// 2050.431 us; speedup vs baseline: 1.8607x; 1.2211x over previous
//
#include <hip/hip_runtime.h>
#include <stdint.h>

#define TAGS 29
#define START_TAG 27
#define STOP_TAG 28
#define BB 64
#define LL 1024
#define DD 1024
#define HH 512
#define FSTRIDE 32   // padded feats row stride (floats)

typedef float f2 __attribute__((ext_vector_type(2)));

// Packed f32 ops via inline asm: VOP3P v_pk_*_f32 = 2 independent IEEE f32
// lanes (same rounding as v_mul_f32/v_add_f32) -> bit-identical to scalar.
__device__ __forceinline__ f2 pk_mul(f2 a, f2 b) {
  f2 d; asm("v_pk_mul_f32 %0, %1, %2" : "=v"(d) : "v"(a), "v"(b)); return d;
}
__device__ __forceinline__ f2 pk_add(f2 a, f2 b) {
  f2 d; asm("v_pk_add_f32 %0, %1, %2" : "=v"(d) : "v"(a), "v"(b)); return d;
}

// ---------------------------------------------------------------------------
// XLA EmitFastTanh clone, f32, with_fma=false. PROVEN bit-exact (r3..r9).
// ---------------------------------------------------------------------------
__device__ __forceinline__ float xla_tanh_f32(float x) {
#pragma clang fp contract(off)
  const float kMax = 7.90531110763549805f;
  float xc = fminf(fmaxf(x, -kMax), kMax);
  float x2 = xc * xc;
  float p = x2 * -2.76076847742355e-16f + 2.00018790482477e-13f;
  p = x2 * p + -8.60467152213735e-11f;
  p = x2 * p + 5.12229709037114e-08f;
  p = x2 * p + 1.48572235717979e-05f;
  p = x2 * p + 6.37261928875436e-04f;
  p = x2 * p + 4.89352455891786e-03f;
  p = xc * p;
  float q = x2 * 1.19825839466702e-06f + 1.18534705686654e-04f;
  q = x2 * q + 2.26843463243900e-03f;
  q = x2 * q + 4.89352518554385e-03f;
  float r = p / q;                       // IEEE div
  return (fabsf(x) < 4.0e-4f) ? x : r;
}

// ---------------------------------------------------------------------------
// Async global->LDS staging of one K-tile (kb..kb+31). Zero staging VGPRs.
// buf floats: [0..2047]      xs = X[row0..row0+63][kb..kb+31], row-major [64][32]
//             [2048..18431]  wl = W1[kb..kb+31][0..511],       row-major [32][512]
// Dest rule (m104): wave-uniform LDS base + lane*16 added by HW.
//   X: wave w (tid<512) rows 8w..8w+7 -> base w*1024B, lane l -> +16l  (linear)
//   W: flat 64KB copy, iter m: float m*4096+tid*4 -> byte 8192+m*16384+tid*16
// ---------------------------------------------------------------------------
__device__ __forceinline__ void stage_tile(const float* __restrict__ X,
                                           const float* __restrict__ W1,
                                           float* buf, int row0, int kb, int tid) {
  const int wid = tid >> 6;
  if (tid < 512) {
    const float* src = X + (size_t)(row0 + (tid >> 3)) * DD + kb + (tid & 7) * 4;
    __builtin_amdgcn_global_load_lds(
        (const __attribute__((address_space(1))) void*)src,
        (__attribute__((address_space(3))) void*)((char*)buf + wid * 1024),
        16, 0, 0);
  }
#pragma unroll
  for (int m = 0; m < 4; ++m) {
    const float* src = W1 + (size_t)kb * HH + m * 4096 + tid * 4;
    __builtin_amdgcn_global_load_lds(
        (const __attribute__((address_space(1))) void*)src,
        (__attribute__((address_space(3))) void*)((char*)buf + 8192 + m * 16384 + wid * 1024),
        16, 0, 0);
  }
}

// ---------------------------------------------------------------------------
// Kernel 1: fused MLP  feats = tanh(X@W1 + b1) @ W2 + b2
// 1024 threads, 64 rows x 512 cols/block, 4 rows x 8 cols per thread
// (acc[4][4] f2 = 32 VGPR, r9-proven no-spill budget).
// NEW vs r9: (a) double-buffered global_load_lds staging, ONE barrier/tile,
// loads in flight across the whole compute phase (m97 pattern);
// (b) inline-asm v_pk math (compiler never emitted it from ext-vector code).
// Numerics IDENTICAL to r9: per-output k-ascending mul-then-add chain.
// ---------------------------------------------------------------------------
__global__ __launch_bounds__(1024) void mlp_kernel(
    const float* __restrict__ X, const float* __restrict__ W1,
    const float* __restrict__ b1, const float* __restrict__ W2,
    const float* __restrict__ b2, float* __restrict__ feats)
{
#pragma clang fp contract(off)
  __shared__ __align__(16) float smem[36864];   // 2 x 18432 floats = 147456 B
  float* hs = smem;                             // [64][260] epilogue overlay

  const int tid  = threadIdx.x;
  const int row0 = blockIdx.x * 64;
  const int rg = tid >> 6;        // 0..15 row-group (wave-uniform)
  const int cg = tid & 63;        // 0..63 col-group

  f2 acc[4][4];                   // rows rg*4+i; cols {cg*4 | 256+cg*4} packed
#pragma unroll
  for (int i = 0; i < 4; ++i)
#pragma unroll
    for (int j = 0; j < 4; ++j) acc[i][j] = (f2)(0.f);

  stage_tile(X, W1, smem, row0, 0, tid);
  __syncthreads();                // barrier drains vmcnt(0): tile 0 ready

  for (int kt = 0; kt < 32; ++kt) {
    const int cur = kt & 1;
    if (kt + 1 < 32)              // issue next tile's loads; they fly under
      stage_tile(X, W1, smem + (cur ^ 1) * 18432, row0, (kt + 1) * 32, tid);

    const float* xsb = smem + cur * 18432;      // [64][32]
    const float* wlb = xsb + 2048;              // [32][512]
#pragma unroll
    for (int kk4 = 0; kk4 < 8; ++kk4) {
      float4 a4[4];
#pragma unroll
      for (int i = 0; i < 4; ++i)               // broadcast reads (rg uniform)
        a4[i] = *(const float4*)(xsb + (rg * 4 + i) * 32 + kk4 * 4);
#pragma unroll
      for (int dk = 0; dk < 4; ++dk) {
        const int k = kk4 * 4 + dk;
        float4 b0  = *(const float4*)(wlb + k * HH + cg * 4);        // contig b128
        float4 b1v = *(const float4*)(wlb + k * HH + 256 + cg * 4);  // contig b128
        f2 bv[4] = {{b0.x, b0.y}, {b0.z, b0.w}, {b1v.x, b1v.y}, {b1v.z, b1v.w}};
#pragma unroll
        for (int i = 0; i < 4; ++i) {
          float a = (dk == 0) ? a4[i].x : (dk == 1) ? a4[i].y
                  : (dk == 2) ? a4[i].z : a4[i].w;
          f2 ai = {a, a};
#pragma unroll
          for (int j = 0; j < 4; ++j)
            acc[i][j] = pk_add(acc[i][j], pk_mul(ai, bv[j]));  // mul-round, add-round
        }
      }
    }
    __syncthreads();  // all reads of buf[cur] done; next tile's loads drained
  }

  float sum[2] = {0.f, 0.f};

  // ---- phase A: h cols 0..255 ----  (hs overlays buf0; safe after final barrier)
  {
    const int c0 = cg * 4;
#pragma unroll
    for (int i = 0; i < 4; ++i) {
      int r = rg * 4 + i;
      float4 hv;
      hv.x = xla_tanh_f32(acc[i][0].x + b1[c0 + 0]);
      hv.y = xla_tanh_f32(acc[i][0].y + b1[c0 + 1]);
      hv.z = xla_tanh_f32(acc[i][1].x + b1[c0 + 2]);
      hv.w = xla_tanh_f32(acc[i][1].y + b1[c0 + 3]);
      *(float4*)(hs + r * 260 + c0) = hv;
    }
  }
  __syncthreads();
#pragma unroll
  for (int it = 0; it < 2; ++it) {
    int idx = tid + it * 1024;
    if (idx < 64 * TAGS) {
      int r = idx & 63, c = idx >> 6;        // c wave-uniform -> W2 scalarizes
      float s = 0.f;
#pragma unroll 4
      for (int k4 = 0; k4 < 64; ++k4) {
        float4 h4 = *(float4*)(hs + r * 260 + k4 * 4);
        float p0 = h4.x * W2[(k4 * 4 + 0) * TAGS + c]; s = s + p0;
        float p1 = h4.y * W2[(k4 * 4 + 1) * TAGS + c]; s = s + p1;
        float p2 = h4.z * W2[(k4 * 4 + 2) * TAGS + c]; s = s + p2;
        float p3 = h4.w * W2[(k4 * 4 + 3) * TAGS + c]; s = s + p3;
      }
      sum[it] = s;
    }
  }
  __syncthreads();

  // ---- phase B: h cols 256..511 ----
  {
    const int c0 = cg * 4;
#pragma unroll
    for (int i = 0; i < 4; ++i) {
      int r = rg * 4 + i;
      float4 hv;
      hv.x = xla_tanh_f32(acc[i][2].x + b1[256 + c0 + 0]);
      hv.y = xla_tanh_f32(acc[i][2].y + b1[256 + c0 + 1]);
      hv.z = xla_tanh_f32(acc[i][3].x + b1[256 + c0 + 2]);
      hv.w = xla_tanh_f32(acc[i][3].y + b1[256 + c0 + 3]);
      *(float4*)(hs + r * 260 + c0) = hv;
    }
  }
  __syncthreads();
#pragma unroll
  for (int it = 0; it < 2; ++it) {
    int idx = tid + it * 1024;
    if (idx < 64 * TAGS) {
      int r = idx & 63, c = idx >> 6;
      float s = sum[it];
#pragma unroll 4
      for (int k4 = 0; k4 < 64; ++k4) {
        float4 h4 = *(float4*)(hs + r * 260 + k4 * 4);
        float p0 = h4.x * W2[(256 + k4 * 4 + 0) * TAGS + c]; s = s + p0;
        float p1 = h4.y * W2[(256 + k4 * 4 + 1) * TAGS + c]; s = s + p1;
        float p2 = h4.z * W2[(256 + k4 * 4 + 2) * TAGS + c]; s = s + p2;
        float p3 = h4.w * W2[(256 + k4 * 4 + 3) * TAGS + c]; s = s + p3;
      }
      feats[(size_t)(row0 + r) * FSTRIDE + c] = s + b2[c];
    }
  }
}

// ---------------------------------------------------------------------------
// Kernel 2: top-1 Viterbi — BYTE-FOR-BYTE the r9 kernel (passed, absmax=0,
// ~220 us). Emissions staged per 64-step chunk; 29-wide argmax as 4 ascending
// chunks of 8, strict-'>' merge == lowest-index tie-break. DO NOT TOUCH.
// ---------------------------------------------------------------------------
__global__ __launch_bounds__(64)
__attribute__((amdgpu_waves_per_eu(1, 4)))
void viterbi_kernel(
    const float* __restrict__ feats, const float* __restrict__ trans,
    int* __restrict__ out)
{
#pragma clang fp contract(off)
  const int b = blockIdx.x;
  const int lane = threadIdx.x;
  const bool act = lane < TAGS;
  __shared__ unsigned char bp[LL][32];       // 32 KB back-pointers
  __shared__ __align__(16) float em[2048];   // 8 KB: 64 steps x 32 tags
  __shared__ __align__(16) float pbuf[32];

  float tr[TAGS];
  const int tl = act ? lane : 0;
#pragma unroll
  for (int f = 0; f < TAGS; ++f) tr[f] = trans[f * TAGS + tl];

  const float* frow = feats + (size_t)b * LL * FSTRIDE;
  float part = act ? (frow[lane] + tr[START_TAG]) : -3.0e38f;
  if (lane >= TAGS && lane < 32) pbuf[lane] = -3.0e38f;   // pad slots, once

  for (int tc = 0; tc < LL / 64; ++tc) {
    {
      const float* flat = frow + tc * 2048;
#pragma unroll
      for (int i = 0; i < 8; ++i) {
        float4 v4 = *(const float4*)(flat + lane * 4 + i * 256);
        *(float4*)(em + lane * 4 + i * 256) = v4;
      }
    }
    const int t0c = (tc == 0) ? 1 : tc * 64;
    const int t1c = tc * 64 + 64;
    for (int t = t0c; t < t1c; ++t) {
      float fv = em[((t & 63) << 5) + lane];
      if (act) pbuf[lane] = part;              // same-wave LDS: in-order
      const float4* pq = (const float4*)pbuf;
      float bvv = -3.0e38f;
      int bii = 0;
#pragma unroll
      for (int cch = 0; cch < 4; ++cch) {
        float4 sA = pq[cch * 2 + 0];
        float4 sB = pq[cch * 2 + 1];
        float s8[8] = {sA.x, sA.y, sA.z, sA.w, sB.x, sB.y, sB.z, sB.w};
        float v8[8];
#pragma unroll
        for (int j = 0; j < 8; ++j) {
          int fr = cch * 8 + j;
          v8[j] = (fr < TAGS) ? ((fv + tr[fr]) + s8[j]) : -3.0e38f;
        }
        float t4[4]; int i4[4];
#pragma unroll
        for (int i = 0; i < 4; ++i) { bool w = v8[2*i+1] > v8[2*i];
          t4[i] = w ? v8[2*i+1] : v8[2*i]; i4[i] = w ? 2*i+1 : 2*i; }
        float t2[2]; int i2[2];
#pragma unroll
        for (int i = 0; i < 2; ++i) { bool w = t4[2*i+1] > t4[2*i];
          t2[i] = w ? t4[2*i+1] : t4[2*i]; i2[i] = w ? i4[2*i+1] : i4[2*i]; }
        bool w = t2[1] > t2[0];
        float cv = w ? t2[1] : t2[0];
        int   ci = (w ? i2[1] : i2[0]) + cch * 8;
        if (cv > bvv) { bvv = cv; bii = ci; }
      }
      part = bvv;
      if (act) bp[t][lane] = (unsigned char)bii;
    }
  }

  float best = -3.0e38f;
  int p0 = 0;
#pragma unroll
  for (int fr = 0; fr < TAGS; ++fr) {
    float s = __shfl(part, fr, 64);
    float v = s + trans[fr * TAGS + STOP_TAG];
    if (v > best) { best = v; p0 = fr; }
  }

  __syncthreads();
  if (lane == 0) {
    int* ob = out + (size_t)b * LL;
    int p = p0;
    ob[LL - 1] = p;
    for (int t = LL - 1; t >= 1; --t) {
      p = bp[t][p];
      ob[t - 1] = p;
    }
  }
}

// ---------------------------------------------------------------------------
extern "C" void kernel_launch(void* const* d_in, const int* in_sizes, int n_in,
                              void* d_out, int out_size, void* d_ws, size_t ws_size,
                              hipStream_t stream) {
  const float* X  = (const float*)d_in[0];
  const float* W1 = (const float*)d_in[2];
  const float* b1 = (const float*)d_in[3];
  const float* W2 = (const float*)d_in[4];
  const float* b2 = (const float*)d_in[5];
  const float* tr = (const float*)d_in[6];

  float* feats = (float*)d_ws;          // (B*L) x 32 padded fp32 rows = 8 MB
  int* out = (int*)d_out;

  mlp_kernel<<<dim3(BB * LL / 64), dim3(1024), 0, stream>>>(X, W1, b1, W2, b2, feats);
  viterbi_kernel<<<dim3(BB), dim3(64), 0, stream>>>(feats, tr, out);
}

// Round 11
// 1992.034 us; speedup vs baseline: 1.9152x; 1.0293x over previous
//
#include <hip/hip_runtime.h>
#include <stdint.h>

#define TAGS 29
#define START_TAG 27
#define STOP_TAG 28
#define BB 64
#define LL 1024
#define DD 1024
#define HH 512
#define FSTRIDE 32   // padded feats row stride (floats)

typedef float f2 __attribute__((ext_vector_type(2)));
struct f4view { f2 lo, hi; };

// ---------------------------------------------------------------------------
// Tied VOP3P MAC: acc += broadcast(aPair[SEL]) * b, exactly 2 VALU instrs,
// no movs/copies. op_sel broadcasts src0.lo (SEL=0) or src0.hi (SEL=1) to
// both result lanes; v_pk_*_f32 lanes are independent IEEE f32 ops with the
// same rounding as v_mul_f32/v_add_f32 -> bit-identical to scalar mul+add.
// ---------------------------------------------------------------------------
template <int SEL>
__device__ __forceinline__ void pk_mac(f2& acc, f2 aPair, f2 b) {
  f2 t;
  if constexpr (SEL == 0)
    asm("v_pk_mul_f32 %0, %2, %3 op_sel:[0,0] op_sel_hi:[0,1]\n\t"
        "v_pk_add_f32 %1, %1, %0"
        : "=&v"(t), "+v"(acc) : "v"(aPair), "v"(b));
  else
    asm("v_pk_mul_f32 %0, %2, %3 op_sel:[1,0] op_sel_hi:[1,1]\n\t"
        "v_pk_add_f32 %1, %1, %0"
        : "=&v"(t), "+v"(acc) : "v"(aPair), "v"(b));
}

// ---------------------------------------------------------------------------
// XLA EmitFastTanh clone, f32, with_fma=false. PROVEN bit-exact (r3..r10).
// ---------------------------------------------------------------------------
__device__ __forceinline__ float xla_tanh_f32(float x) {
#pragma clang fp contract(off)
  const float kMax = 7.90531110763549805f;
  float xc = fminf(fmaxf(x, -kMax), kMax);
  float x2 = xc * xc;
  float p = x2 * -2.76076847742355e-16f + 2.00018790482477e-13f;
  p = x2 * p + -8.60467152213735e-11f;
  p = x2 * p + 5.12229709037114e-08f;
  p = x2 * p + 1.48572235717979e-05f;
  p = x2 * p + 6.37261928875436e-04f;
  p = x2 * p + 4.89352455891786e-03f;
  p = xc * p;
  float q = x2 * 1.19825839466702e-06f + 1.18534705686654e-04f;
  q = x2 * q + 2.26843463243900e-03f;
  q = x2 * q + 4.89352518554385e-03f;
  float r = p / q;                       // IEEE div
  return (fabsf(x) < 4.0e-4f) ? x : r;
}

// ---------------------------------------------------------------------------
// Async global->LDS staging of one K-tile (kb..kb+31). Zero staging VGPRs.
// buf floats: [0..2047]      xs = X[row0..row0+63][kb..kb+31], row-major [64][32]
//             [2048..18431]  wl = W1[kb..kb+31][0..511],       row-major [32][512]
// Dest = wave-uniform LDS base + lane*16 (HW rule); both layouts linear.
// PROVEN r10 (absmax=0).
// ---------------------------------------------------------------------------
__device__ __forceinline__ void stage_tile(const float* __restrict__ X,
                                           const float* __restrict__ W1,
                                           float* buf, int row0, int kb, int tid) {
  const int wid = tid >> 6;
  if (tid < 512) {
    const float* src = X + (size_t)(row0 + (tid >> 3)) * DD + kb + (tid & 7) * 4;
    __builtin_amdgcn_global_load_lds(
        (const __attribute__((address_space(1))) void*)src,
        (__attribute__((address_space(3))) void*)((char*)buf + wid * 1024),
        16, 0, 0);
  }
#pragma unroll
  for (int m = 0; m < 4; ++m) {
    const float* src = W1 + (size_t)kb * HH + m * 4096 + tid * 4;
    __builtin_amdgcn_global_load_lds(
        (const __attribute__((address_space(1))) void*)src,
        (__attribute__((address_space(3))) void*)((char*)buf + 8192 + m * 16384 + wid * 1024),
        16, 0, 0);
  }
}

// ---------------------------------------------------------------------------
// Kernel 1: fused MLP  feats = tanh(X@W1 + b1) @ W2 + b2
// r10 structure (1024 thr, 64x512 tile, 4x8/thread, dbuf gload_lds staging).
// ONLY change vs r10: the inner MAC is the tied op_sel pk_mac (2 VALU/MAC,
// no movs) instead of untied pk_mul/pk_add wrappers. Same per-output
// k-ascending mul-round/add-round chain -> feats bit-identical.
// ---------------------------------------------------------------------------
__global__ __launch_bounds__(1024) void mlp_kernel(
    const float* __restrict__ X, const float* __restrict__ W1,
    const float* __restrict__ b1, const float* __restrict__ W2,
    const float* __restrict__ b2, float* __restrict__ feats)
{
#pragma clang fp contract(off)
  __shared__ __align__(16) float smem[36864];   // 2 x 18432 floats = 147456 B
  float* hs = smem;                             // [64][260] epilogue overlay

  const int tid  = threadIdx.x;
  const int row0 = blockIdx.x * 64;
  const int rg = tid >> 6;        // 0..15 row-group (wave index, uniform)
  const int cg = tid & 63;        // 0..63 col-group

  f2 acc[4][4];                   // rows rg*4+i; cols {cg*4 | 256+cg*4} packed
#pragma unroll
  for (int i = 0; i < 4; ++i)
#pragma unroll
    for (int j = 0; j < 4; ++j) acc[i][j] = (f2)(0.f);

  stage_tile(X, W1, smem, row0, 0, tid);
  __syncthreads();                // barrier drains vmcnt(0): tile 0 ready

  for (int kt = 0; kt < 32; ++kt) {
    const int cur = kt & 1;
    if (kt + 1 < 32)              // issue next tile's loads; they fly under
      stage_tile(X, W1, smem + (cur ^ 1) * 18432, row0, (kt + 1) * 32, tid);

    const float* xsb = smem + cur * 18432;      // [64][32]
    const float* wlb = xsb + 2048;              // [32][512]
#pragma unroll
    for (int kk4 = 0; kk4 < 8; ++kk4) {
      float4 a4[4];
#pragma unroll
      for (int i = 0; i < 4; ++i)               // broadcast reads (rg uniform)
        a4[i] = *(const float4*)(xsb + (rg * 4 + i) * 32 + kk4 * 4);
#pragma unroll
      for (int dk = 0; dk < 4; ++dk) {
        const int k = kk4 * 4 + dk;
        float4 b0  = *(const float4*)(wlb + k * HH + cg * 4);        // contig b128
        float4 b1v = *(const float4*)(wlb + k * HH + 256 + cg * 4);  // contig b128
        f4view bva = __builtin_bit_cast(f4view, b0);
        f4view bvb = __builtin_bit_cast(f4view, b1v);
        f2 bv[4] = {bva.lo, bva.hi, bvb.lo, bvb.hi};
#pragma unroll
        for (int i = 0; i < 4; ++i) {
          f4view av = __builtin_bit_cast(f4view, a4[i]);
          f2 ap = (dk < 2) ? av.lo : av.hi;     // pair holding k's scalar
#pragma unroll
          for (int j = 0; j < 4; ++j) {
            if (dk & 1) pk_mac<1>(acc[i][j], ap, bv[j]);
            else        pk_mac<0>(acc[i][j], ap, bv[j]);
          }
        }
      }
    }
    __syncthreads();  // all reads of buf[cur] done; next tile's loads drained
  }

  float sum[2] = {0.f, 0.f};

  // ---- phase A: h cols 0..255 ----  (hs overlays buf0; safe after barrier)
  {
    const int c0 = cg * 4;
#pragma unroll
    for (int i = 0; i < 4; ++i) {
      int r = rg * 4 + i;
      float4 hv;
      hv.x = xla_tanh_f32(acc[i][0].x + b1[c0 + 0]);
      hv.y = xla_tanh_f32(acc[i][0].y + b1[c0 + 1]);
      hv.z = xla_tanh_f32(acc[i][1].x + b1[c0 + 2]);
      hv.w = xla_tanh_f32(acc[i][1].y + b1[c0 + 3]);
      *(float4*)(hs + r * 260 + c0) = hv;
    }
  }
  __syncthreads();
#pragma unroll
  for (int it = 0; it < 2; ++it) {
    int idx = tid + it * 1024;
    if (idx < 64 * TAGS) {
      int r = idx & 63, c = idx >> 6;        // c wave-uniform -> W2 scalarizes
      float s = 0.f;
#pragma unroll 4
      for (int k4 = 0; k4 < 64; ++k4) {
        float4 h4 = *(float4*)(hs + r * 260 + k4 * 4);
        float p0 = h4.x * W2[(k4 * 4 + 0) * TAGS + c]; s = s + p0;
        float p1 = h4.y * W2[(k4 * 4 + 1) * TAGS + c]; s = s + p1;
        float p2 = h4.z * W2[(k4 * 4 + 2) * TAGS + c]; s = s + p2;
        float p3 = h4.w * W2[(k4 * 4 + 3) * TAGS + c]; s = s + p3;
      }
      sum[it] = s;
    }
  }
  __syncthreads();

  // ---- phase B: h cols 256..511 ----
  {
    const int c0 = cg * 4;
#pragma unroll
    for (int i = 0; i < 4; ++i) {
      int r = rg * 4 + i;
      float4 hv;
      hv.x = xla_tanh_f32(acc[i][2].x + b1[256 + c0 + 0]);
      hv.y = xla_tanh_f32(acc[i][2].y + b1[256 + c0 + 1]);
      hv.z = xla_tanh_f32(acc[i][3].x + b1[256 + c0 + 2]);
      hv.w = xla_tanh_f32(acc[i][3].y + b1[256 + c0 + 3]);
      *(float4*)(hs + r * 260 + c0) = hv;
    }
  }
  __syncthreads();
#pragma unroll
  for (int it = 0; it < 2; ++it) {
    int idx = tid + it * 1024;
    if (idx < 64 * TAGS) {
      int r = idx & 63, c = idx >> 6;
      float s = sum[it];
#pragma unroll 4
      for (int k4 = 0; k4 < 64; ++k4) {
        float4 h4 = *(float4*)(hs + r * 260 + k4 * 4);
        float p0 = h4.x * W2[(256 + k4 * 4 + 0) * TAGS + c]; s = s + p0;
        float p1 = h4.y * W2[(256 + k4 * 4 + 1) * TAGS + c]; s = s + p1;
        float p2 = h4.z * W2[(256 + k4 * 4 + 2) * TAGS + c]; s = s + p2;
        float p3 = h4.w * W2[(256 + k4 * 4 + 3) * TAGS + c]; s = s + p3;
      }
      feats[(size_t)(row0 + r) * FSTRIDE + c] = s + b2[c];
    }
  }
}

// ---------------------------------------------------------------------------
// Kernel 2: top-1 Viterbi — BYTE-FOR-BYTE the r9/r10 kernel (passed,
// absmax=0, ~300 us). DO NOT TOUCH.
// ---------------------------------------------------------------------------
__global__ __launch_bounds__(64)
__attribute__((amdgpu_waves_per_eu(1, 4)))
void viterbi_kernel(
    const float* __restrict__ feats, const float* __restrict__ trans,
    int* __restrict__ out)
{
#pragma clang fp contract(off)
  const int b = blockIdx.x;
  const int lane = threadIdx.x;
  const bool act = lane < TAGS;
  __shared__ unsigned char bp[LL][32];       // 32 KB back-pointers
  __shared__ __align__(16) float em[2048];   // 8 KB: 64 steps x 32 tags
  __shared__ __align__(16) float pbuf[32];

  float tr[TAGS];
  const int tl = act ? lane : 0;
#pragma unroll
  for (int f = 0; f < TAGS; ++f) tr[f] = trans[f * TAGS + tl];

  const float* frow = feats + (size_t)b * LL * FSTRIDE;
  float part = act ? (frow[lane] + tr[START_TAG]) : -3.0e38f;
  if (lane >= TAGS && lane < 32) pbuf[lane] = -3.0e38f;   // pad slots, once

  for (int tc = 0; tc < LL / 64; ++tc) {
    {
      const float* flat = frow + tc * 2048;
#pragma unroll
      for (int i = 0; i < 8; ++i) {
        float4 v4 = *(const float4*)(flat + lane * 4 + i * 256);
        *(float4*)(em + lane * 4 + i * 256) = v4;
      }
    }
    const int t0c = (tc == 0) ? 1 : tc * 64;
    const int t1c = tc * 64 + 64;
    for (int t = t0c; t < t1c; ++t) {
      float fv = em[((t & 63) << 5) + lane];
      if (act) pbuf[lane] = part;              // same-wave LDS: in-order
      const float4* pq = (const float4*)pbuf;
      float bvv = -3.0e38f;
      int bii = 0;
#pragma unroll
      for (int cch = 0; cch < 4; ++cch) {
        float4 sA = pq[cch * 2 + 0];
        float4 sB = pq[cch * 2 + 1];
        float s8[8] = {sA.x, sA.y, sA.z, sA.w, sB.x, sB.y, sB.z, sB.w};
        float v8[8];
#pragma unroll
        for (int j = 0; j < 8; ++j) {
          int fr = cch * 8 + j;
          v8[j] = (fr < TAGS) ? ((fv + tr[fr]) + s8[j]) : -3.0e38f;
        }
        float t4[4]; int i4[4];
#pragma unroll
        for (int i = 0; i < 4; ++i) { bool w = v8[2*i+1] > v8[2*i];
          t4[i] = w ? v8[2*i+1] : v8[2*i]; i4[i] = w ? 2*i+1 : 2*i; }
        float t2[2]; int i2[2];
#pragma unroll
        for (int i = 0; i < 2; ++i) { bool w = t4[2*i+1] > t4[2*i];
          t2[i] = w ? t4[2*i+1] : t4[2*i]; i2[i] = w ? i4[2*i+1] : i4[2*i]; }
        bool w = t2[1] > t2[0];
        float cv = w ? t2[1] : t2[0];
        int   ci = (w ? i2[1] : i2[0]) + cch * 8;
        if (cv > bvv) { bvv = cv; bii = ci; }
      }
      part = bvv;
      if (act) bp[t][lane] = (unsigned char)bii;
    }
  }

  float best = -3.0e38f;
  int p0 = 0;
#pragma unroll
  for (int fr = 0; fr < TAGS; ++fr) {
    float s = __shfl(part, fr, 64);
    float v = s + trans[fr * TAGS + STOP_TAG];
    if (v > best) { best = v; p0 = fr; }
  }

  __syncthreads();
  if (lane == 0) {
    int* ob = out + (size_t)b * LL;
    int p = p0;
    ob[LL - 1] = p;
    for (int t = LL - 1; t >= 1; --t) {
      p = bp[t][p];
      ob[t - 1] = p;
    }
  }
}

// ---------------------------------------------------------------------------
extern "C" void kernel_launch(void* const* d_in, const int* in_sizes, int n_in,
                              void* d_out, int out_size, void* d_ws, size_t ws_size,
                              hipStream_t stream) {
  const float* X  = (const float*)d_in[0];
  const float* W1 = (const float*)d_in[2];
  const float* b1 = (const float*)d_in[3];
  const float* W2 = (const float*)d_in[4];
  const float* b2 = (const float*)d_in[5];
  const float* tr = (const float*)d_in[6];

  float* feats = (float*)d_ws;          // (B*L) x 32 padded fp32 rows = 8 MB
  int* out = (int*)d_out;

  mlp_kernel<<<dim3(BB * LL / 64), dim3(1024), 0, stream>>>(X, W1, b1, W2, b2, feats);
  viterbi_kernel<<<dim3(BB), dim3(64), 0, stream>>>(feats, tr, out);
}

// Round 13
// 1792.296 us; speedup vs baseline: 2.1287x; 1.1114x over previous
//
#include <hip/hip_runtime.h>
#include <stdint.h>

#define TAGS 29
#define START_TAG 27
#define STOP_TAG 28
#define BB 64
#define LL 1024
#define DD 1024
#define HH 512
#define FSTRIDE 32   // padded feats row stride (floats)

typedef float f2 __attribute__((ext_vector_type(2)));
struct f4view { f2 lo, hi; };

// ---------------------------------------------------------------------------
// Tied VOP3P MAC: acc += broadcast(aPair[SEL]) * b. 2 VALU instrs, no movs.
// v_pk lanes are independent IEEE f32 (same rounding as v_mul/v_add) ->
// bit-identical to scalar mul-then-add. PROVEN r11 (absmax=0).
// ---------------------------------------------------------------------------
template <int SEL>
__device__ __forceinline__ void pk_mac(f2& acc, f2 aPair, f2 b) {
  f2 t;
  if constexpr (SEL == 0)
    asm("v_pk_mul_f32 %0, %2, %3 op_sel:[0,0] op_sel_hi:[0,1]\n\t"
        "v_pk_add_f32 %1, %1, %0"
        : "=&v"(t), "+v"(acc) : "v"(aPair), "v"(b));
  else
    asm("v_pk_mul_f32 %0, %2, %3 op_sel:[1,0] op_sel_hi:[1,1]\n\t"
        "v_pk_add_f32 %1, %1, %0"
        : "=&v"(t), "+v"(acc) : "v"(aPair), "v"(b));
}

// ---------------------------------------------------------------------------
// XLA EmitFastTanh clone, f32, with_fma=false. PROVEN bit-exact (r3..r11).
// ---------------------------------------------------------------------------
__device__ __forceinline__ float xla_tanh_f32(float x) {
#pragma clang fp contract(off)
  const float kMax = 7.90531110763549805f;
  float xc = fminf(fmaxf(x, -kMax), kMax);
  float x2 = xc * xc;
  float p = x2 * -2.76076847742355e-16f + 2.00018790482477e-13f;
  p = x2 * p + -8.60467152213735e-11f;
  p = x2 * p + 5.12229709037114e-08f;
  p = x2 * p + 1.48572235717979e-05f;
  p = x2 * p + 6.37261928875436e-04f;
  p = x2 * p + 4.89352455891786e-03f;
  p = xc * p;
  float q = x2 * 1.19825839466702e-06f + 1.18534705686654e-04f;
  q = x2 * q + 2.26843463243900e-03f;
  q = x2 * q + 4.89352518554385e-03f;
  float r = p / q;                       // IEEE div
  return (fabsf(x) < 4.0e-4f) ? x : r;
}

// ---------------------------------------------------------------------------
// Async global->LDS staging of one K-tile (kb..kb+15). Zero staging VGPRs.
// buf floats: [0..1023]     xs = X[row0..row0+63][kb..kb+15], row-major [64][16]
//             [1024..9215]  wl = W1[kb..kb+15][0..511],       row-major [16][512]
// Dest = wave-uniform base + lane*16 (HW rule); both layouts linear.
//   X: threads 0..255, dest byte t*16  -> row t>>2, colq t&3 (per-lane src)
//   W: all 512 threads, m=0..3: dest 4096 + m*8192 + t*16 (flat 32 KB copy)
// ---------------------------------------------------------------------------
__device__ __forceinline__ void stage_tile(const float* __restrict__ X,
                                           const float* __restrict__ W1,
                                           float* buf, int row0, int kb, int tid) {
  const int wid = tid >> 6;
  if (tid < 256) {
    const float* src = X + (size_t)(row0 + (tid >> 2)) * DD + kb + (tid & 3) * 4;
    __builtin_amdgcn_global_load_lds(
        (const __attribute__((address_space(1))) void*)src,
        (__attribute__((address_space(3))) void*)((char*)buf + wid * 1024),
        16, 0, 0);
  }
#pragma unroll
  for (int m = 0; m < 4; ++m) {
    const float* src = W1 + (size_t)kb * HH + m * 2048 + tid * 4;
    __builtin_amdgcn_global_load_lds(
        (const __attribute__((address_space(1))) void*)src,
        (__attribute__((address_space(3))) void*)((char*)buf + 4096 + m * 8192 + wid * 1024),
        16, 0, 0);
  }
}

// ---------------------------------------------------------------------------
// Kernel 1: fused MLP  feats = tanh(X@W1 + b1) @ W2 + b2
// 512 threads (8 waves), 64 rows x 512 cols/block, 8 rows x 8 cols/thread:
// doubles MAC/LDS-byte reuse vs r11 -> LDS B-traffic 8192->4096 cyc/kt/CU
// (was co-saturated with VALU). K-tile 16, double-buffered gload_lds,
// 72 KB LDS -> 2 blocks/CU (cross-block overlap hides staging+barrier skew).
// waves_per_eu(4,..) -> VGPR cap 128, live ~114, no spill.
// Numerics IDENTICAL to r9/r10/r11 (absmax=0): per-output k-ascending
// mul-round/add-round chain; pk lanes independent IEEE f32.
// ---------------------------------------------------------------------------
__global__ __launch_bounds__(512)
__attribute__((amdgpu_waves_per_eu(4, 8)))
void mlp_kernel(
    const float* __restrict__ X, const float* __restrict__ W1,
    const float* __restrict__ b1, const float* __restrict__ W2,
    const float* __restrict__ b2, float* __restrict__ feats)
{
#pragma clang fp contract(off)
  __shared__ __align__(16) float smem[18432];   // 2 x 9216 floats = 73728 B
  float* hs = smem;                             // [64][260] epilogue overlay

  const int tid  = threadIdx.x;
  const int row0 = blockIdx.x * 64;
  const int rg = tid >> 6;        // wave id 0..7 -> rows rg*8..rg*8+7
  const int cg = tid & 63;        // cols {cg*4..+3} u {256+cg*4..+3}

  f2 acc[8][4];                   // 8 rows x (4+4 packed cols) = 64 VGPR
#pragma unroll
  for (int i = 0; i < 8; ++i)
#pragma unroll
    for (int j = 0; j < 4; ++j) acc[i][j] = (f2)(0.f);

  stage_tile(X, W1, smem, row0, 0, tid);
  __syncthreads();                // compiler drains vmcnt before barrier

  for (int kt = 0; kt < 64; ++kt) {
    const int cur = kt & 1;
    if (kt + 1 < 64)              // next tile's loads fly under compute
      stage_tile(X, W1, smem + (cur ^ 1) * 9216, row0, (kt + 1) * 16, tid);

    const float* xsb = smem + cur * 9216;       // [64][16]
    const float* wlb = xsb + 1024;              // [16][512]
#pragma unroll
    for (int kk4 = 0; kk4 < 4; ++kk4) {
      float4 a4[8];
#pragma unroll
      for (int i = 0; i < 8; ++i)               // broadcast reads (rg uniform)
        a4[i] = *(const float4*)(xsb + (rg * 8 + i) * 16 + kk4 * 4);
#pragma unroll
      for (int dk = 0; dk < 4; ++dk) {
        const int k = kk4 * 4 + dk;
        float4 b0  = *(const float4*)(wlb + k * HH + cg * 4);        // contig b128
        float4 b1v = *(const float4*)(wlb + k * HH + 256 + cg * 4);  // contig b128
        f4view bva = __builtin_bit_cast(f4view, b0);
        f4view bvb = __builtin_bit_cast(f4view, b1v);
        f2 bv[4] = {bva.lo, bva.hi, bvb.lo, bvb.hi};
#pragma unroll
        for (int i = 0; i < 8; ++i) {
          f4view av = __builtin_bit_cast(f4view, a4[i]);
          f2 ap = (dk < 2) ? av.lo : av.hi;     // pair holding k's scalar
#pragma unroll
          for (int j = 0; j < 4; ++j) {
            if (dk & 1) pk_mac<1>(acc[i][j], ap, bv[j]);
            else        pk_mac<0>(acc[i][j], ap, bv[j]);
          }
        }
      }
    }
    __syncthreads();  // buf[cur] reads done; staged loads drained
  }

  float sum[4] = {0.f, 0.f, 0.f, 0.f};

  // ---- phase A: h cols 0..255 ----  (hs overlays buf0; safe after barrier)
  {
    const int c0 = cg * 4;
#pragma unroll
    for (int i = 0; i < 8; ++i) {
      int r = rg * 8 + i;
      float4 hv;
      hv.x = xla_tanh_f32(acc[i][0].x + b1[c0 + 0]);
      hv.y = xla_tanh_f32(acc[i][0].y + b1[c0 + 1]);
      hv.z = xla_tanh_f32(acc[i][1].x + b1[c0 + 2]);
      hv.w = xla_tanh_f32(acc[i][1].y + b1[c0 + 3]);
      *(float4*)(hs + r * 260 + c0) = hv;
    }
  }
  __syncthreads();
#pragma unroll
  for (int it = 0; it < 4; ++it) {
    int idx = tid + it * 512;
    if (idx < 64 * TAGS) {
      int r = idx & 63, c = idx >> 6;        // c wave-uniform -> W2 scalarizes
      float s = 0.f;
#pragma unroll 4
      for (int k4 = 0; k4 < 64; ++k4) {
        float4 h4 = *(float4*)(hs + r * 260 + k4 * 4);
        float p0 = h4.x * W2[(k4 * 4 + 0) * TAGS + c]; s = s + p0;
        float p1 = h4.y * W2[(k4 * 4 + 1) * TAGS + c]; s = s + p1;
        float p2 = h4.z * W2[(k4 * 4 + 2) * TAGS + c]; s = s + p2;
        float p3 = h4.w * W2[(k4 * 4 + 3) * TAGS + c]; s = s + p3;
      }
      sum[it] = s;
    }
  }
  __syncthreads();

  // ---- phase B: h cols 256..511 ----
  {
    const int c0 = cg * 4;
#pragma unroll
    for (int i = 0; i < 8; ++i) {
      int r = rg * 8 + i;
      float4 hv;
      hv.x = xla_tanh_f32(acc[i][2].x + b1[256 + c0 + 0]);
      hv.y = xla_tanh_f32(acc[i][2].y + b1[256 + c0 + 1]);
      hv.z = xla_tanh_f32(acc[i][3].x + b1[256 + c0 + 2]);
      hv.w = xla_tanh_f32(acc[i][3].y + b1[256 + c0 + 3]);
      *(float4*)(hs + r * 260 + c0) = hv;
    }
  }
  __syncthreads();
#pragma unroll
  for (int it = 0; it < 4; ++it) {
    int idx = tid + it * 512;
    if (idx < 64 * TAGS) {
      int r = idx & 63, c = idx >> 6;
      float s = sum[it];
#pragma unroll 4
      for (int k4 = 0; k4 < 64; ++k4) {
        float4 h4 = *(float4*)(hs + r * 260 + k4 * 4);
        float p0 = h4.x * W2[(256 + k4 * 4 + 0) * TAGS + c]; s = s + p0;
        float p1 = h4.y * W2[(256 + k4 * 4 + 1) * TAGS + c]; s = s + p1;
        float p2 = h4.z * W2[(256 + k4 * 4 + 2) * TAGS + c]; s = s + p2;
        float p3 = h4.w * W2[(256 + k4 * 4 + 3) * TAGS + c]; s = s + p3;
      }
      feats[(size_t)(row0 + r) * FSTRIDE + c] = s + b2[c];
    }
  }
}

// ---------------------------------------------------------------------------
// Kernel 2: top-1 Viterbi — BYTE-FOR-BYTE the r9/r10/r11 kernel (passed,
// absmax=0). DO NOT TOUCH.
// ---------------------------------------------------------------------------
__global__ __launch_bounds__(64)
__attribute__((amdgpu_waves_per_eu(1, 4)))
void viterbi_kernel(
    const float* __restrict__ feats, const float* __restrict__ trans,
    int* __restrict__ out)
{
#pragma clang fp contract(off)
  const int b = blockIdx.x;
  const int lane = threadIdx.x;
  const bool act = lane < TAGS;
  __shared__ unsigned char bp[LL][32];       // 32 KB back-pointers
  __shared__ __align__(16) float em[2048];   // 8 KB: 64 steps x 32 tags
  __shared__ __align__(16) float pbuf[32];

  float tr[TAGS];
  const int tl = act ? lane : 0;
#pragma unroll
  for (int f = 0; f < TAGS; ++f) tr[f] = trans[f * TAGS + tl];

  const float* frow = feats + (size_t)b * LL * FSTRIDE;
  float part = act ? (frow[lane] + tr[START_TAG]) : -3.0e38f;
  if (lane >= TAGS && lane < 32) pbuf[lane] = -3.0e38f;   // pad slots, once

  for (int tc = 0; tc < LL / 64; ++tc) {
    {
      const float* flat = frow + tc * 2048;
#pragma unroll
      for (int i = 0; i < 8; ++i) {
        float4 v4 = *(const float4*)(flat + lane * 4 + i * 256);
        *(float4*)(em + lane * 4 + i * 256) = v4;
      }
    }
    const int t0c = (tc == 0) ? 1 : tc * 64;
    const int t1c = tc * 64 + 64;
    for (int t = t0c; t < t1c; ++t) {
      float fv = em[((t & 63) << 5) + lane];
      if (act) pbuf[lane] = part;              // same-wave LDS: in-order
      const float4* pq = (const float4*)pbuf;
      float bvv = -3.0e38f;
      int bii = 0;
#pragma unroll
      for (int cch = 0; cch < 4; ++cch) {
        float4 sA = pq[cch * 2 + 0];
        float4 sB = pq[cch * 2 + 1];
        float s8[8] = {sA.x, sA.y, sA.z, sA.w, sB.x, sB.y, sB.z, sB.w};
        float v8[8];
#pragma unroll
        for (int j = 0; j < 8; ++j) {
          int fr = cch * 8 + j;
          v8[j] = (fr < TAGS) ? ((fv + tr[fr]) + s8[j]) : -3.0e38f;
        }
        float t4[4]; int i4[4];
#pragma unroll
        for (int i = 0; i < 4; ++i) { bool w = v8[2*i+1] > v8[2*i];
          t4[i] = w ? v8[2*i+1] : v8[2*i]; i4[i] = w ? 2*i+1 : 2*i; }
        float t2[2]; int i2[2];
#pragma unroll
        for (int i = 0; i < 2; ++i) { bool w = t4[2*i+1] > t4[2*i];
          t2[i] = w ? t4[2*i+1] : t4[2*i]; i2[i] = w ? i4[2*i+1] : i4[2*i]; }
        bool w = t2[1] > t2[0];
        float cv = w ? t2[1] : t2[0];
        int   ci = (w ? i2[1] : i2[0]) + cch * 8;
        if (cv > bvv) { bvv = cv; bii = ci; }
      }
      part = bvv;
      if (act) bp[t][lane] = (unsigned char)bii;
    }
  }

  float best = -3.0e38f;
  int p0 = 0;
#pragma unroll
  for (int fr = 0; fr < TAGS; ++fr) {
    float s = __shfl(part, fr, 64);
    float v = s + trans[fr * TAGS + STOP_TAG];
    if (v > best) { best = v; p0 = fr; }
  }

  __syncthreads();
  if (lane == 0) {
    int* ob = out + (size_t)b * LL;
    int p = p0;
    ob[LL - 1] = p;
    for (int t = LL - 1; t >= 1; --t) {
      p = bp[t][p];
      ob[t - 1] = p;
    }
  }
}

// ---------------------------------------------------------------------------
extern "C" void kernel_launch(void* const* d_in, const int* in_sizes, int n_in,
                              void* d_out, int out_size, void* d_ws, size_t ws_size,
                              hipStream_t stream) {
  const float* X  = (const float*)d_in[0];
  const float* W1 = (const float*)d_in[2];
  const float* b1 = (const float*)d_in[3];
  const float* W2 = (const float*)d_in[4];
  const float* b2 = (const float*)d_in[5];
  const float* tr = (const float*)d_in[6];

  float* feats = (float*)d_ws;          // (B*L) x 32 padded fp32 rows = 8 MB
  int* out = (int*)d_out;

  mlp_kernel<<<dim3(BB * LL / 64), dim3(512), 0, stream>>>(X, W1, b1, W2, b2, feats);
  viterbi_kernel<<<dim3(BB), dim3(64), 0, stream>>>(feats, tr, out);
}